// Round 5
// baseline (3151.532 us; speedup 1.0000x reference)
//
#include <hip/hip_runtime.h>
#include <math.h>

#define TT 64
#define FF 32
#define HH 64
#define NN 8      // nodes per block
#define G4 256    // 4*H gate rows
#define GG1 64
#define GG2 32

typedef float f32x4 __attribute__((ext_vector_type(4)));

__device__ __forceinline__ float fexp2(float x){ return __builtin_amdgcn_exp2f(x); }
__device__ __forceinline__ float frcp (float x){ return __builtin_amdgcn_rcpf(x); }
// sigm(v) = 1/(1+2^(-v*log2e)) ; tanh(v) = 1 - 2/(1+2^(2v*log2e))
__device__ __forceinline__ float sigm (float v){ return frcp(1.0f + fexp2(-1.442695041f*v)); }
__device__ __forceinline__ float ftanh(float v){ return fmaf(-2.0f, frcp(1.0f + fexp2(2.885390082f*v)), 1.0f); }

// sum across the 4 lanes of a quad via DPP quad_perm (VALU pipe, no LDS)
__device__ __forceinline__ float quad_reduce(float v){
  int a  = __builtin_bit_cast(int, v);
  int b  = __builtin_amdgcn_update_dpp(0, a, 0xB1, 0xF, 0xF, true);  // quad swap 1
  float s = v + __builtin_bit_cast(float, b);
  int c  = __builtin_bit_cast(int, s);
  int d  = __builtin_amdgcn_update_dpp(0, c, 0x4E, 0xF, 0xF, true);  // quad swap 2
  return s + __builtin_bit_cast(float, d);
}

__device__ __forceinline__ float dp4(f32x4 a, f32x4 b, float acc){
  acc = fmaf(a[0], b[0], acc);
  acc = fmaf(a[1], b[1], acc);
  acc = fmaf(a[2], b[2], acc);
  return fmaf(a[3], b[3], acc);
}

// compile-time-indexed 4-way select (no dynamic register-array indexing)
__device__ __forceinline__ float sel4(float a0, float a1, float a2, float a3, int q){
  float x = (q & 1) ? a1 : a0;
  float y = (q & 1) ? a3 : a2;
  return (q & 2) ? y : x;
}

#define PIN(v) asm volatile("" : "+v"(v))

// ---------------------------------------------------------------------------
// Fused 2-layer LSTM. Block = 1024 threads = 256 gate rows x 4 K-quarters,
// NN=8 nodes/block. Layer-1 weights (128 KB) live in LDS (XOR-swizzled
// (row&7)<<4 so the 16-rows-per-wave ds_read_b128 is ~2-way = free).
// Layer-0 weights are only 24 floats/thread -> register-resident under any
// budget. x staged per-timestep (2 KB double buffer, prefetched 1 iter
// ahead). LDS total 142 KB -> 1 block/CU, 4 waves/EU.
// ---------------------------------------------------------------------------
__global__ __launch_bounds__(1024, 4)
void lstm_fused(
    const float* __restrict__ x,
    const float* __restrict__ Wih0, const float* __restrict__ Whh0,
    const float* __restrict__ bih0, const float* __restrict__ bhh0,
    const float* __restrict__ Wih1, const float* __restrict__ Whh1,
    const float* __restrict__ bih1, const float* __restrict__ bhh1,
    float* __restrict__ hout, int n)
{
  const int tid = threadIdx.x;
  const int r   = tid >> 2;     // gate row 0..255
  const int q   = tid & 3;      // K-quarter 0..3
  const int nA  = blockIdx.x * NN;

  __shared__ float wls0[G4][HH];     // Wih1, swizzled (64 KB)
  __shared__ float wls1[G4][HH];     // Whh1, swizzled (64 KB)
  __shared__ float gs [NN][G4];      // 8 KB
  __shared__ float h0s[NN][HH];      // 2 KB
  __shared__ float h1s[NN][HH];      // 2 KB
  __shared__ float xs2[2][NN][FF];   // 2 KB, double-buffered per-t x

  int avail = n - nA; if (avail > NN) avail = NN;

  // ---- stage layer-1 weights into LDS, swizzled: byte ^= (row&7)<<4 ----
  {
    const f32x4* gw1 = (const f32x4*)Wih1;
    const f32x4* gw2 = (const f32x4*)Whh1;
    char* b0p = (char*)&wls0[0][0];
    char* b1p = (char*)&wls1[0][0];
#pragma unroll
    for (int u = 0; u < 4; ++u) {
      const int m = tid*4 + u;                    // quad index 0..4095
      const int rr = m >> 4;                      // row
      const unsigned byte = (unsigned)(m << 4);
      const unsigned swz  = byte ^ (unsigned)((rr & 7) << 4);
      *(f32x4*)(b0p + swz) = gw1[m];
      *(f32x4*)(b1p + swz) = gw2[m];
    }
  }

  // ---- layer-0 weight quarter-rows -> registers (6 quads = 24 floats) ----
  f32x4 wi0[2], wh0[4];
  {
    const f32x4* a = (const f32x4*)&Wih0[r*FF + q*8];
    wi0[0] = a[0]; wi0[1] = a[1];
    const f32x4* b = (const f32x4*)&Whh0[r*HH + q*16];
    wh0[0] = b[0]; wh0[1] = b[1]; wh0[2] = b[2]; wh0[3] = b[3];
  }
  float b0 = bih0[r] + bhh0[r];
  float b1 = bih1[r] + bhh1[r];

  // stage x(t=0); zero h state
  if (tid < NN*FF) {
    const int nd = tid >> 5, f = tid & 31;
    xs2[0][nd][f] = (nd < avail) ? x[((size_t)(nA+nd)*TT + 0)*FF + f] : 0.0f;
  }
  if (tid < NN*HH) { (&h0s[0][0])[tid] = 0.0f; (&h1s[0][0])[tid] = 0.0f; }
  float cell0 = 0.0f, cell1 = 0.0f;   // cell state of (nd,m)=(tid>>6,tid&63), tid<512

  PIN(wi0[0]); PIN(wi0[1]);
  PIN(wh0[0]); PIN(wh0[1]); PIN(wh0[2]); PIN(wh0[3]);
  PIN(b0); PIN(b1);
  __syncthreads();

  const char* w0b = (const char*)&wls0[0][0];
  const char* w1b = (const char*)&wls1[0][0];
  const unsigned wb = (unsigned)(r*256 + q*64);
  const unsigned sx = (unsigned)((r & 7) << 4);

  float a[NN];
  for (int t = 0; t < TT; ++t) {
    // prefetch x(t+1) into the other buffer (lands during this iteration)
    if (tid < NN*FF) {
      const int nd = tid >> 5, f = tid & 31;
      const int tn = t + 1;
      if (tn < TT)
        xs2[tn & 1][nd][f] = (nd < avail) ? x[((size_t)(nA+nd)*TT + tn)*FF + f] : 0.0f;
    }

    // ---------- layer 0: gate row r, quarter q, nodes 0..7 ----------
#pragma unroll
    for (int nd = 0; nd < NN; ++nd) {
      const f32x4* xv = (const f32x4*)&xs2[t & 1][nd][q*8];
      const f32x4* hv = (const f32x4*)&h0s[nd][q*16];
      float s = 0.0f;
      { f32x4 v0 = xv[0], v1 = xv[1]; s = dp4(v0, wi0[0], s); s = dp4(v1, wi0[1], s); }
      { f32x4 v0 = hv[0], v1 = hv[1]; s = dp4(v0, wh0[0], s); s = dp4(v1, wh0[1], s); }
      { f32x4 v0 = hv[2], v1 = hv[3]; s = dp4(v0, wh0[2], s); s = dp4(v1, wh0[3], s); }
      a[nd] = s;
    }
#pragma unroll
    for (int nd = 0; nd < NN; ++nd) a[nd] = quad_reduce(a[nd]);
    {
      float u = sel4(a[0], a[1], a[2], a[3], q) + b0;   // lane q owns node q
      float v = sel4(a[4], a[5], a[6], a[7], q) + b0;   // and node q+4
      gs[q    ][r] = u;
      gs[q + 4][r] = v;
    }
    __syncthreads();

    if (tid < NN*HH) {
      const int nd = tid >> 6, m = tid & 63;
      const float gi = gs[nd][m], gf = gs[nd][m+64], gg = gs[nd][m+128], go = gs[nd][m+192];
      cell0 = sigm(gf)*cell0 + sigm(gi)*ftanh(gg);
      h0s[nd][m] = sigm(go)*ftanh(cell0);
    }
    __syncthreads();

    // ---------- layer 1: weights from swizzled LDS ----------
    {
      f32x4 wi1q0 = *(const f32x4*)(w0b + ((wb +  0) ^ sx));
      f32x4 wi1q1 = *(const f32x4*)(w0b + ((wb + 16) ^ sx));
      f32x4 wi1q2 = *(const f32x4*)(w0b + ((wb + 32) ^ sx));
      f32x4 wi1q3 = *(const f32x4*)(w0b + ((wb + 48) ^ sx));
      f32x4 wh1q0 = *(const f32x4*)(w1b + ((wb +  0) ^ sx));
      f32x4 wh1q1 = *(const f32x4*)(w1b + ((wb + 16) ^ sx));
      f32x4 wh1q2 = *(const f32x4*)(w1b + ((wb + 32) ^ sx));
      f32x4 wh1q3 = *(const f32x4*)(w1b + ((wb + 48) ^ sx));
#pragma unroll
      for (int nd = 0; nd < NN; ++nd) {
        const f32x4* pv = (const f32x4*)&h0s[nd][q*16];
        const f32x4* qv = (const f32x4*)&h1s[nd][q*16];
        float s = 0.0f;
        { f32x4 v0 = pv[0], v1 = pv[1]; s = dp4(v0, wi1q0, s); s = dp4(v1, wi1q1, s); }
        { f32x4 v0 = pv[2], v1 = pv[3]; s = dp4(v0, wi1q2, s); s = dp4(v1, wi1q3, s); }
        { f32x4 v0 = qv[0], v1 = qv[1]; s = dp4(v0, wh1q0, s); s = dp4(v1, wh1q1, s); }
        { f32x4 v0 = qv[2], v1 = qv[3]; s = dp4(v0, wh1q2, s); s = dp4(v1, wh1q3, s); }
        a[nd] = s;
      }
    }
#pragma unroll
    for (int nd = 0; nd < NN; ++nd) a[nd] = quad_reduce(a[nd]);
    {
      float u = sel4(a[0], a[1], a[2], a[3], q) + b1;
      float v = sel4(a[4], a[5], a[6], a[7], q) + b1;
      gs[q    ][r] = u;
      gs[q + 4][r] = v;
    }
    __syncthreads();

    if (tid < NN*HH) {
      const int nd = tid >> 6, m = tid & 63;
      const float gi = gs[nd][m], gf = gs[nd][m+64], gg = gs[nd][m+128], go = gs[nd][m+192];
      cell1 = sigm(gf)*cell1 + sigm(gi)*ftanh(gg);
      h1s[nd][m] = sigm(go)*ftanh(cell1);
    }
    __syncthreads();
  }

  if (tid < NN*HH) {
    const int nd = tid >> 6, m = tid & 63;
    const int node = nA + nd;
    if (node < n) hout[(size_t)node*HH + m] = h1s[nd][m];
  }
}

// ---------------------------------------------------------------------------
// GCN support kernels (unchanged — not the bottleneck)
// ---------------------------------------------------------------------------
__global__ void k_count(const int* __restrict__ dst, int E, int* __restrict__ cnt)
{
  int e = blockIdx.x * blockDim.x + threadIdx.x;
  if (e < E) atomicAdd(&cnt[dst[e]], 1);
}

__global__ void k_scan_build(const int* __restrict__ cnt, int n,
                             int* __restrict__ offs, int* __restrict__ cursor,
                             float* __restrict__ dinv)
{
  __shared__ int part[1024];
  const int tid = threadIdx.x;
  const int per = (n + 1023) >> 10;
  const int base = tid * per;
  int s = 0;
  for (int i = 0; i < per; ++i) { int idx = base + i; if (idx < n) s += cnt[idx]; }
  part[tid] = s;
  __syncthreads();
  for (int off = 1; off < 1024; off <<= 1) {
    int v = 0;
    if (tid >= off) v = part[tid - off];
    __syncthreads();
    part[tid] += v;
    __syncthreads();
  }
  int run = part[tid] - s;
  for (int i = 0; i < per; ++i) {
    int idx = base + i;
    if (idx < n) {
      offs[idx] = run; cursor[idx] = run;
      int c = cnt[idx];
      dinv[idx] = 1.0f / sqrtf((float)(c + 1));
      run += c;
    }
  }
}

__global__ void k_fill(const int* __restrict__ src, const int* __restrict__ dst,
                       int E, int* __restrict__ cursor, int* __restrict__ csr)
{
  int e = blockIdx.x * blockDim.x + threadIdx.x;
  if (e < E) {
    int d = dst[e];
    int pos = atomicAdd(&cursor[d], 1);
    csr[pos] = src[e];
  }
}

template <int K, int M>
__global__ void k_xw(const float* __restrict__ A, const float* __restrict__ W,
                     float* __restrict__ out, int n)
{
  int idx = blockIdx.x * blockDim.x + threadIdx.x;
  int row = idx / M, col = idx % M;
  if (row >= n) return;
  const float* a = A + (size_t)row * K;
  float acc = 0.0f;
#pragma unroll
  for (int k = 0; k < K; ++k) acc = fmaf(a[k], W[k*M + col], acc);
  out[(size_t)row*M + col] = acc;
}

template <int FD>
__global__ void k_agg(const float* __restrict__ xw, const int* __restrict__ offs,
                      const int* __restrict__ cnt, const int* __restrict__ csr,
                      const float* __restrict__ dinv, const float* __restrict__ b,
                      float* __restrict__ out, int n)
{
  int gidx = blockIdx.x * blockDim.x + threadIdx.x;
  int node = gidx / FD, lane = gidx % FD;
  if (node >= n) return;
  const float di = dinv[node];
  float acc = xw[(size_t)node*FD + lane] * di * di;
  const int s0 = offs[node], e0 = s0 + cnt[node];
  for (int p = s0; p < e0; ++p) {
    int s = csr[p];
    acc = fmaf(xw[(size_t)s*FD + lane], dinv[s] * di, acc);
  }
  out[(size_t)node*FD + lane] = fmaxf(acc + b[lane], 0.0f);
}

__global__ void k_fc(const float* __restrict__ g2, const int* __restrict__ sid,
                     const float* __restrict__ fcW, const float* __restrict__ fcb,
                     float* __restrict__ out, int n)
{
  int i = blockIdx.x * blockDim.x + threadIdx.x;
  if (i >= n) return;
  const float* row = g2 + (size_t)sid[i] * GG2;
  float acc = fcb[0];
#pragma unroll
  for (int f = 0; f < GG2; ++f) acc = fmaf(row[f], fcW[f], acc);
  out[i] = acc;
}

// ---------------------------------------------------------------------------
extern "C" void kernel_launch(void* const* d_in, const int* in_sizes, int n_in,
                              void* d_out, int out_size, void* d_ws, size_t ws_size,
                              hipStream_t stream)
{
  const float* x    = (const float*)d_in[0];
  const int*   sid  = (const int*)  d_in[1];
  const int*   eidx = (const int*)  d_in[2];
  const float* Wih0 = (const float*)d_in[3];
  const float* Whh0 = (const float*)d_in[4];
  const float* bih0 = (const float*)d_in[5];
  const float* bhh0 = (const float*)d_in[6];
  const float* Wih1 = (const float*)d_in[7];
  const float* Whh1 = (const float*)d_in[8];
  const float* bih1 = (const float*)d_in[9];
  const float* bhh1 = (const float*)d_in[10];
  const float* g1W  = (const float*)d_in[11];
  const float* g1b  = (const float*)d_in[12];
  const float* g2W  = (const float*)d_in[13];
  const float* g2b  = (const float*)d_in[14];
  const float* fcW  = (const float*)d_in[15];
  const float* fcb  = (const float*)d_in[16];

  const int n = in_sizes[1];
  const int E = in_sizes[2] / 2;
  float* out = (float*)d_out;

  char* w = (char*)d_ws;
  auto carve = [&](size_t bytes) -> void* {
    void* p = (void*)w; w += (bytes + 255) & ~(size_t)255; return p;
  };
  float* hfin   = (float*)carve((size_t)n * HH * 4);
  int*   cnt    = (int*)  carve((size_t)n * 4);
  int*   offs   = (int*)  carve((size_t)n * 4);
  int*   cursor = (int*)  carve((size_t)n * 4);
  float* dinv   = (float*)carve((size_t)n * 4);
  int*   csr    = (int*)  carve((size_t)E * 4);
  float* xw1    = (float*)carve((size_t)n * GG1 * 4);
  float* g1     = (float*)carve((size_t)n * GG1 * 4);
  float* xw2    = (float*)carve((size_t)n * GG2 * 4);
  float* g2     = (float*)carve((size_t)n * GG2 * 4);

  const int* src = eidx;
  const int* dst = eidx + E;

  lstm_fused<<<(n + NN - 1) / NN, 1024, 0, stream>>>(x, Wih0, Whh0, bih0, bhh0,
                                                     Wih1, Whh1, bih1, bhh1, hfin, n);

  hipMemsetAsync(cnt, 0, (size_t)n * 4, stream);
  k_count<<<(E + 255) / 256, 256, 0, stream>>>(dst, E, cnt);
  k_scan_build<<<1, 1024, 0, stream>>>(cnt, n, offs, cursor, dinv);
  k_fill<<<(E + 255) / 256, 256, 0, stream>>>(src, dst, E, cursor, csr);

  k_xw<HH, GG1><<<((size_t)n * GG1 + 255) / 256, 256, 0, stream>>>(hfin, g1W, xw1, n);
  k_agg<GG1><<<((size_t)n * GG1 + 255) / 256, 256, 0, stream>>>(xw1, offs, cnt, csr, dinv, g1b, g1, n);

  k_xw<GG1, GG2><<<((size_t)n * GG2 + 255) / 256, 256, 0, stream>>>(g1, g2W, xw2, n);
  k_agg<GG2><<<((size_t)n * GG2 + 255) / 256, 256, 0, stream>>>(xw2, offs, cnt, csr, dinv, g2b, g2, n);

  k_fc<<<(n + 255) / 256, 256, 0, stream>>>(g2, sid, fcW, fcb, out, n);
}

// Round 6
// 2591.950 us; speedup vs baseline: 1.2159x; 1.2159x over previous
//
#include <hip/hip_runtime.h>
#include <math.h>

#define TT 64
#define FF 32
#define HH 64
#define NN 8      // nodes per block
#define G4 256    // 4*H gate rows
#define HP 80     // padded h row (quarter q at float offset q*20 -> disjoint banks)
#define GP 264    // padded gs row (2-way max on writer scatter)
#define GG1 64
#define GG2 32

typedef float f32x4 __attribute__((ext_vector_type(4)));

__device__ __forceinline__ float fexp2(float x){ return __builtin_amdgcn_exp2f(x); }
__device__ __forceinline__ float frcp (float x){ return __builtin_amdgcn_rcpf(x); }
__device__ __forceinline__ float sigm (float v){ return frcp(1.0f + fexp2(-1.442695041f*v)); }
__device__ __forceinline__ float ftanh(float v){ return fmaf(-2.0f, frcp(1.0f + fexp2(2.885390082f*v)), 1.0f); }

__device__ __forceinline__ float quad_reduce(float v){
  int a  = __builtin_bit_cast(int, v);
  int b  = __builtin_amdgcn_update_dpp(0, a, 0xB1, 0xF, 0xF, true);
  float s = v + __builtin_bit_cast(float, b);
  int c  = __builtin_bit_cast(int, s);
  int d  = __builtin_amdgcn_update_dpp(0, c, 0x4E, 0xF, 0xF, true);
  return s + __builtin_bit_cast(float, d);
}

__device__ __forceinline__ float dp4(f32x4 a, f32x4 b, float acc){
  acc = fmaf(a[0], b[0], acc);
  acc = fmaf(a[1], b[1], acc);
  acc = fmaf(a[2], b[2], acc);
  return fmaf(a[3], b[3], acc);
}

__device__ __forceinline__ float sel4(float a0, float a1, float a2, float a3, int q){
  float x = (q & 1) ? a1 : a0;
  float y = (q & 1) ? a3 : a2;
  return (q & 2) ? y : x;
}

// un-rematerializable register pin (volatile asm def cannot be re-executed)
#define PIN(v) asm volatile("" : "+v"(v))
// volatile global load: pinned at def, never remat'd
#define GL(dst, base, OFF) \
  asm volatile("global_load_dwordx4 %0, %1, off offset:" OFF : "=v"(dst) : "v"(base))

// ---------------------------------------------------------------------------
// Fused 2-layer LSTM, software-pipelined: per iteration compute
// [ L1 gates(t) + L0 gates(t+1) ] (they share the h0(t) operand reads),
// then ONE combine phase using all 1024 threads (low half: layer-0 cell of
// t+1; high half: layer-1 cell of t). 2 barriers per timestep.
// L0 weights: volatile-asm-pinned registers (24 floats). L1 weights: LDS
// (XOR-swizzled), read once per t and pinned. h rows padded to 80 floats so
// the 4-broadcast-address ds_read_b128 quarters hit disjoint banks.
// ---------------------------------------------------------------------------
__global__ __launch_bounds__(1024, 4)
void lstm_fused(
    const float* __restrict__ x,
    const float* __restrict__ Wih0, const float* __restrict__ Whh0,
    const float* __restrict__ bih0, const float* __restrict__ bhh0,
    const float* __restrict__ Wih1, const float* __restrict__ Whh1,
    const float* __restrict__ bih1, const float* __restrict__ bhh1,
    float* __restrict__ hout, int n)
{
  const int tid = threadIdx.x;
  const int r   = tid >> 2;     // gate row 0..255
  const int q   = tid & 3;      // K-quarter 0..3
  const int nA  = blockIdx.x * NN;

  __shared__ float wls0[G4*HH];      // Wih1, swizzled (64 KB)
  __shared__ float wls1[G4*HH];      // Whh1, swizzled (64 KB)
  __shared__ float gs0[NN][GP];      // layer-0 gates (8.25 KB)
  __shared__ float gs1[NN][GP];      // layer-1 gates
  __shared__ float h0s[NN][HP];      // 2.5 KB
  __shared__ float h1s[NN][HP];
  __shared__ float xs2[2][NN][FF];   // 2 KB double-buffered x

  int avail = n - nA; if (avail > NN) avail = NN;

  // ---- stage layer-1 weights into LDS, swizzled: byte ^= (row&7)<<4 ----
  {
    const f32x4* gw1 = (const f32x4*)Wih1;
    const f32x4* gw2 = (const f32x4*)Whh1;
    char* b0p = (char*)wls0;
    char* b1p = (char*)wls1;
#pragma unroll
    for (int u = 0; u < 4; ++u) {
      const int m = tid*4 + u;
      const int rr = m >> 4;
      const unsigned byte = (unsigned)(m << 4);
      const unsigned swz  = byte ^ (unsigned)((rr & 7) << 4);
      *(f32x4*)(b0p + swz) = gw1[m];
      *(f32x4*)(b1p + swz) = gw2[m];
    }
  }

  // ---- layer-0 weights: volatile-pinned registers (6 quads) ----
  const float* pWi0 = Wih0 + r*FF + q*8;
  const float* pWh0 = Whh0 + r*HH + q*16;
  f32x4 wi0[2], wh0[4];
  GL(wi0[0], pWi0, "0");  GL(wi0[1], pWi0, "16");
  GL(wh0[0], pWh0, "0");  GL(wh0[1], pWh0, "16");
  GL(wh0[2], pWh0, "32"); GL(wh0[3], pWh0, "48");
  float b0 = bih0[r] + bhh0[r];
  float b1 = bih1[r] + bhh1[r];
  PIN(b0); PIN(b1);

  // stage x(0); zero h state
  if (tid < NN*FF) {
    const int nd = tid >> 5, f = tid & 31;
    xs2[0][nd][f] = (nd < avail) ? x[((size_t)(nA+nd)*TT + 0)*FF + f] : 0.0f;
  }
  if (tid < NN*HP) { (&h0s[0][0])[tid] = 0.0f; (&h1s[0][0])[tid] = 0.0f; }
  float cell = 0.0f;   // low threads: layer-0 cell; high threads: layer-1 cell

  asm volatile("s_waitcnt vmcnt(0)" ::: "memory");
  __builtin_amdgcn_sched_barrier(0);
  __syncthreads();

  const char* w0b = (const char*)wls0;
  const char* w1b = (const char*)wls1;
  const unsigned wb = (unsigned)(r*256 + q*64);
  const unsigned sx = (unsigned)((r & 7) << 4);

  // =================== prologue: L0 gates(0) ===================
  {
    if (tid < NN*FF) {   // prefetch x(1)
      const int nd = tid >> 5, f = tid & 31;
      xs2[1][nd][f] = (nd < avail) ? x[((size_t)(nA+nd)*TT + 1)*FF + f] : 0.0f;
    }
    float a0[NN];
#pragma unroll
    for (int nd = 0; nd < NN; ++nd) {
      const f32x4* xv = (const f32x4*)&xs2[0][nd][q*8];
      const f32x4* hv = (const f32x4*)&h0s[nd][q*20];
      float s0 = 0.0f;
      { f32x4 va = xv[0], vb = xv[1]; s0 = dp4(va, wi0[0], s0); s0 = dp4(vb, wi0[1], s0); }
      { f32x4 va = hv[0], vb = hv[1], vc = hv[2], vd = hv[3];
        s0 = dp4(va, wh0[0], s0); s0 = dp4(vb, wh0[1], s0);
        s0 = dp4(vc, wh0[2], s0); s0 = dp4(vd, wh0[3], s0); }
      a0[nd] = s0;
    }
#pragma unroll
    for (int nd = 0; nd < NN; ++nd) a0[nd] = quad_reduce(a0[nd]);
    gs0[q    ][r] = sel4(a0[0], a0[1], a0[2], a0[3], q) + b0;
    gs0[q + 4][r] = sel4(a0[4], a0[5], a0[6], a0[7], q) + b0;
  }
  __syncthreads();
  if (tid < 512) {
    const int nd = tid >> 6, m = tid & 63;
    const float gi = gs0[nd][m], gf = gs0[nd][m+64], gg = gs0[nd][m+128], go = gs0[nd][m+192];
    cell = sigm(gf)*cell + sigm(gi)*ftanh(gg);
    h0s[nd][(m>>4)*20 + (m&15)] = sigm(go)*ftanh(cell);
  }
  __syncthreads();

  // =================== main loop: L1(t) + L0(t+1) ===================
  for (int t = 0; t < TT-1; ++t) {
    if (tid < NN*FF) {   // prefetch x(t+2)
      const int nd = tid >> 5, f = tid & 31;
      const int tn = t + 2;
      if (tn < TT)
        xs2[tn & 1][nd][f] = (nd < avail) ? x[((size_t)(nA+nd)*TT + tn)*FF + f] : 0.0f;
    }
    // L1 weight quarters from swizzled LDS, pinned for this iteration
    f32x4 u0 = *(const f32x4*)(w0b + ((wb +  0) ^ sx));
    f32x4 u1 = *(const f32x4*)(w0b + ((wb + 16) ^ sx));
    f32x4 u2 = *(const f32x4*)(w0b + ((wb + 32) ^ sx));
    f32x4 u3 = *(const f32x4*)(w0b + ((wb + 48) ^ sx));
    f32x4 v0 = *(const f32x4*)(w1b + ((wb +  0) ^ sx));
    f32x4 v1 = *(const f32x4*)(w1b + ((wb + 16) ^ sx));
    f32x4 v2 = *(const f32x4*)(w1b + ((wb + 32) ^ sx));
    f32x4 v3 = *(const f32x4*)(w1b + ((wb + 48) ^ sx));
    PIN(u0); PIN(u1); PIN(u2); PIN(u3);
    PIN(v0); PIN(v1); PIN(v2); PIN(v3);

    float a0[NN], a1[NN];
    const int bx = (t + 1) & 1;
#pragma unroll
    for (int nd = 0; nd < NN; ++nd) {
      const f32x4* hv = (const f32x4*)&h0s[nd][q*20];
      f32x4 ha = hv[0], hb = hv[1], hc = hv[2], hd = hv[3];
      const f32x4* xv = (const f32x4*)&xs2[bx][nd][q*8];
      f32x4 xa = xv[0], xb = xv[1];
      float s0 = 0.0f, s1 = 0.0f;
      // L0(t+1): x.wi0 + h0.wh0
      s0 = dp4(xa, wi0[0], s0); s0 = dp4(xb, wi0[1], s0);
      s0 = dp4(ha, wh0[0], s0); s0 = dp4(hb, wh0[1], s0);
      s0 = dp4(hc, wh0[2], s0); s0 = dp4(hd, wh0[3], s0);
      // L1(t): h0.wi1 (+ h1.wh1 below)
      s1 = dp4(ha, u0, s1); s1 = dp4(hb, u1, s1);
      s1 = dp4(hc, u2, s1); s1 = dp4(hd, u3, s1);
      const f32x4* qv = (const f32x4*)&h1s[nd][q*20];
      f32x4 qa = qv[0], qb = qv[1], qc = qv[2], qd = qv[3];
      s1 = dp4(qa, v0, s1); s1 = dp4(qb, v1, s1);
      s1 = dp4(qc, v2, s1); s1 = dp4(qd, v3, s1);
      a0[nd] = s0; a1[nd] = s1;
    }
#pragma unroll
    for (int nd = 0; nd < NN; ++nd) { a0[nd] = quad_reduce(a0[nd]); a1[nd] = quad_reduce(a1[nd]); }
    gs0[q    ][r] = sel4(a0[0], a0[1], a0[2], a0[3], q) + b0;
    gs0[q + 4][r] = sel4(a0[4], a0[5], a0[6], a0[7], q) + b0;
    gs1[q    ][r] = sel4(a1[0], a1[1], a1[2], a1[3], q) + b1;
    gs1[q + 4][r] = sel4(a1[4], a1[5], a1[6], a1[7], q) + b1;
    __syncthreads();

    if (tid < 512) {        // layer-0 combine for t+1
      const int nd = tid >> 6, m = tid & 63;
      const float gi = gs0[nd][m], gf = gs0[nd][m+64], gg = gs0[nd][m+128], go = gs0[nd][m+192];
      cell = sigm(gf)*cell + sigm(gi)*ftanh(gg);
      h0s[nd][(m>>4)*20 + (m&15)] = sigm(go)*ftanh(cell);
    } else {                // layer-1 combine for t
      const int tt = tid - 512;
      const int nd = tt >> 6, m = tt & 63;
      const float gi = gs1[nd][m], gf = gs1[nd][m+64], gg = gs1[nd][m+128], go = gs1[nd][m+192];
      cell = sigm(gf)*cell + sigm(gi)*ftanh(gg);
      h1s[nd][(m>>4)*20 + (m&15)] = sigm(go)*ftanh(cell);
    }
    __syncthreads();
  }

  // =================== epilogue: L1 gates(63) + combine ===================
  {
    f32x4 u0 = *(const f32x4*)(w0b + ((wb +  0) ^ sx));
    f32x4 u1 = *(const f32x4*)(w0b + ((wb + 16) ^ sx));
    f32x4 u2 = *(const f32x4*)(w0b + ((wb + 32) ^ sx));
    f32x4 u3 = *(const f32x4*)(w0b + ((wb + 48) ^ sx));
    f32x4 v0 = *(const f32x4*)(w1b + ((wb +  0) ^ sx));
    f32x4 v1 = *(const f32x4*)(w1b + ((wb + 16) ^ sx));
    f32x4 v2 = *(const f32x4*)(w1b + ((wb + 32) ^ sx));
    f32x4 v3 = *(const f32x4*)(w1b + ((wb + 48) ^ sx));
    float a1[NN];
#pragma unroll
    for (int nd = 0; nd < NN; ++nd) {
      const f32x4* hv = (const f32x4*)&h0s[nd][q*20];
      const f32x4* qv = (const f32x4*)&h1s[nd][q*20];
      float s1 = 0.0f;
      { f32x4 va = hv[0], vb = hv[1], vc = hv[2], vd = hv[3];
        s1 = dp4(va, u0, s1); s1 = dp4(vb, u1, s1);
        s1 = dp4(vc, u2, s1); s1 = dp4(vd, u3, s1); }
      { f32x4 va = qv[0], vb = qv[1], vc = qv[2], vd = qv[3];
        s1 = dp4(va, v0, s1); s1 = dp4(vb, v1, s1);
        s1 = dp4(vc, v2, s1); s1 = dp4(vd, v3, s1); }
      a1[nd] = s1;
    }
#pragma unroll
    for (int nd = 0; nd < NN; ++nd) a1[nd] = quad_reduce(a1[nd]);
    gs1[q    ][r] = sel4(a1[0], a1[1], a1[2], a1[3], q) + b1;
    gs1[q + 4][r] = sel4(a1[4], a1[5], a1[6], a1[7], q) + b1;
  }
  __syncthreads();
  if (tid >= 512) {
    const int tt = tid - 512;
    const int nd = tt >> 6, m = tt & 63;
    const float gi = gs1[nd][m], gf = gs1[nd][m+64], gg = gs1[nd][m+128], go = gs1[nd][m+192];
    cell = sigm(gf)*cell + sigm(gi)*ftanh(gg);
    h1s[nd][(m>>4)*20 + (m&15)] = sigm(go)*ftanh(cell);
  }
  __syncthreads();

  if (tid < 512) {
    const int nd = tid >> 6, m = tid & 63;
    const int node = nA + nd;
    if (node < n) hout[(size_t)node*HH + m] = h1s[nd][(m>>4)*20 + (m&15)];
  }
}

// ---------------------------------------------------------------------------
// GCN support kernels (unchanged — not the bottleneck)
// ---------------------------------------------------------------------------
__global__ void k_count(const int* __restrict__ dst, int E, int* __restrict__ cnt)
{
  int e = blockIdx.x * blockDim.x + threadIdx.x;
  if (e < E) atomicAdd(&cnt[dst[e]], 1);
}

__global__ void k_scan_build(const int* __restrict__ cnt, int n,
                             int* __restrict__ offs, int* __restrict__ cursor,
                             float* __restrict__ dinv)
{
  __shared__ int part[1024];
  const int tid = threadIdx.x;
  const int per = (n + 1023) >> 10;
  const int base = tid * per;
  int s = 0;
  for (int i = 0; i < per; ++i) { int idx = base + i; if (idx < n) s += cnt[idx]; }
  part[tid] = s;
  __syncthreads();
  for (int off = 1; off < 1024; off <<= 1) {
    int v = 0;
    if (tid >= off) v = part[tid - off];
    __syncthreads();
    part[tid] += v;
    __syncthreads();
  }
  int run = part[tid] - s;
  for (int i = 0; i < per; ++i) {
    int idx = base + i;
    if (idx < n) {
      offs[idx] = run; cursor[idx] = run;
      int c = cnt[idx];
      dinv[idx] = 1.0f / sqrtf((float)(c + 1));
      run += c;
    }
  }
}

__global__ void k_fill(const int* __restrict__ src, const int* __restrict__ dst,
                       int E, int* __restrict__ cursor, int* __restrict__ csr)
{
  int e = blockIdx.x * blockDim.x + threadIdx.x;
  if (e < E) {
    int d = dst[e];
    int pos = atomicAdd(&cursor[d], 1);
    csr[pos] = src[e];
  }
}

template <int K, int M>
__global__ void k_xw(const float* __restrict__ A, const float* __restrict__ W,
                     float* __restrict__ out, int n)
{
  int idx = blockIdx.x * blockDim.x + threadIdx.x;
  int row = idx / M, col = idx % M;
  if (row >= n) return;
  const float* a = A + (size_t)row * K;
  float acc = 0.0f;
#pragma unroll
  for (int k = 0; k < K; ++k) acc = fmaf(a[k], W[k*M + col], acc);
  out[(size_t)row*M + col] = acc;
}

template <int FD>
__global__ void k_agg(const float* __restrict__ xw, const int* __restrict__ offs,
                      const int* __restrict__ cnt, const int* __restrict__ csr,
                      const float* __restrict__ dinv, const float* __restrict__ b,
                      float* __restrict__ out, int n)
{
  int gidx = blockIdx.x * blockDim.x + threadIdx.x;
  int node = gidx / FD, lane = gidx % FD;
  if (node >= n) return;
  const float di = dinv[node];
  float acc = xw[(size_t)node*FD + lane] * di * di;
  const int s0 = offs[node], e0 = s0 + cnt[node];
  for (int p = s0; p < e0; ++p) {
    int s = csr[p];
    acc = fmaf(xw[(size_t)s*FD + lane], dinv[s] * di, acc);
  }
  out[(size_t)node*FD + lane] = fmaxf(acc + b[lane], 0.0f);
}

__global__ void k_fc(const float* __restrict__ g2, const int* __restrict__ sid,
                     const float* __restrict__ fcW, const float* __restrict__ fcb,
                     float* __restrict__ out, int n)
{
  int i = blockIdx.x * blockDim.x + threadIdx.x;
  if (i >= n) return;
  const float* row = g2 + (size_t)sid[i] * GG2;
  float acc = fcb[0];
#pragma unroll
  for (int f = 0; f < GG2; ++f) acc = fmaf(row[f], fcW[f], acc);
  out[i] = acc;
}

// ---------------------------------------------------------------------------
extern "C" void kernel_launch(void* const* d_in, const int* in_sizes, int n_in,
                              void* d_out, int out_size, void* d_ws, size_t ws_size,
                              hipStream_t stream)
{
  const float* x    = (const float*)d_in[0];
  const int*   sid  = (const int*)  d_in[1];
  const int*   eidx = (const int*)  d_in[2];
  const float* Wih0 = (const float*)d_in[3];
  const float* Whh0 = (const float*)d_in[4];
  const float* bih0 = (const float*)d_in[5];
  const float* bhh0 = (const float*)d_in[6];
  const float* Wih1 = (const float*)d_in[7];
  const float* Whh1 = (const float*)d_in[8];
  const float* bih1 = (const float*)d_in[9];
  const float* bhh1 = (const float*)d_in[10];
  const float* g1W  = (const float*)d_in[11];
  const float* g1b  = (const float*)d_in[12];
  const float* g2W  = (const float*)d_in[13];
  const float* g2b  = (const float*)d_in[14];
  const float* fcW  = (const float*)d_in[15];
  const float* fcb  = (const float*)d_in[16];

  const int n = in_sizes[1];
  const int E = in_sizes[2] / 2;
  float* out = (float*)d_out;

  char* w = (char*)d_ws;
  auto carve = [&](size_t bytes) -> void* {
    void* p = (void*)w; w += (bytes + 255) & ~(size_t)255; return p;
  };
  float* hfin   = (float*)carve((size_t)n * HH * 4);
  int*   cnt    = (int*)  carve((size_t)n * 4);
  int*   offs   = (int*)  carve((size_t)n * 4);
  int*   cursor = (int*)  carve((size_t)n * 4);
  float* dinv   = (float*)carve((size_t)n * 4);
  int*   csr    = (int*)  carve((size_t)E * 4);
  float* xw1    = (float*)carve((size_t)n * GG1 * 4);
  float* g1     = (float*)carve((size_t)n * GG1 * 4);
  float* xw2    = (float*)carve((size_t)n * GG2 * 4);
  float* g2     = (float*)carve((size_t)n * GG2 * 4);

  const int* src = eidx;
  const int* dst = eidx + E;

  lstm_fused<<<(n + NN - 1) / NN, 1024, 0, stream>>>(x, Wih0, Whh0, bih0, bhh0,
                                                     Wih1, Whh1, bih1, bhh1, hfin, n);

  hipMemsetAsync(cnt, 0, (size_t)n * 4, stream);
  k_count<<<(E + 255) / 256, 256, 0, stream>>>(dst, E, cnt);
  k_scan_build<<<1, 1024, 0, stream>>>(cnt, n, offs, cursor, dinv);
  k_fill<<<(E + 255) / 256, 256, 0, stream>>>(src, dst, E, cursor, csr);

  k_xw<HH, GG1><<<((size_t)n * GG1 + 255) / 256, 256, 0, stream>>>(hfin, g1W, xw1, n);
  k_agg<GG1><<<((size_t)n * GG1 + 255) / 256, 256, 0, stream>>>(xw1, offs, cnt, csr, dinv, g1b, g1, n);

  k_xw<GG1, GG2><<<((size_t)n * GG2 + 255) / 256, 256, 0, stream>>>(g1, g2W, xw2, n);
  k_agg<GG2><<<((size_t)n * GG2 + 255) / 256, 256, 0, stream>>>(xw2, offs, cnt, csr, dinv, g2b, g2, n);

  k_fc<<<(n + 255) / 256, 256, 0, stream>>>(g2, sid, fcW, fcb, out, n);
}

// Round 7
// 838.154 us; speedup vs baseline: 3.7601x; 3.0924x over previous
//
#include <hip/hip_runtime.h>
#include <math.h>

#define TT 64
#define FF 32
#define HH 64
#define NN 16     // nodes per block
#define GG1 64
#define GG2 32

typedef float f32x4 __attribute__((ext_vector_type(4)));
typedef short bf16x8 __attribute__((ext_vector_type(8)));

__device__ __forceinline__ float fexp2(float x){ return __builtin_amdgcn_exp2f(x); }
__device__ __forceinline__ float frcp (float x){ return __builtin_amdgcn_rcpf(x); }
__device__ __forceinline__ float sigm (float v){ return frcp(1.0f + fexp2(-1.442695041f*v)); }
__device__ __forceinline__ float ftanh(float v){ return fmaf(-2.0f, frcp(1.0f + fexp2(2.885390082f*v)), 1.0f); }

// round-to-nearest-even fp32 -> bf16 bits
__device__ __forceinline__ unsigned short bf16rn(float x){
  unsigned u = __builtin_bit_cast(unsigned, x);
  return (unsigned short)((u + 0x7FFFu + ((u >> 16) & 1u)) >> 16);
}
// split x = hi + lo (both representable as bf16); hi is RN(x)
__device__ __forceinline__ void split2(float x, unsigned short& h, unsigned short& l){
  unsigned u = __builtin_bit_cast(unsigned, x);
  unsigned hr = (u + 0x7FFFu + ((u >> 16) & 1u)) & 0xFFFF0000u;
  h = (unsigned short)(hr >> 16);
  l = bf16rn(x - __builtin_bit_cast(float, hr));
}

#define PIN(v) asm volatile("" : "+v"(v))
#define MFMA(acc, a, b) (acc) = __builtin_amdgcn_mfma_f32_16x16x32_bf16((a), (b), (acc), 0, 0, 0)

// load 8 consecutive fp32 and split into hi/lo bf16 fragments
__device__ __forceinline__ void wsplit(const float* p, bf16x8& hi, bf16x8& lo){
  float4 a = *(const float4*)p;
  float4 b = *(const float4*)(p + 4);
  unsigned short h, s;
  split2(a.x,h,s); hi[0]=(short)h; lo[0]=(short)s;
  split2(a.y,h,s); hi[1]=(short)h; lo[1]=(short)s;
  split2(a.z,h,s); hi[2]=(short)h; lo[2]=(short)s;
  split2(a.w,h,s); hi[3]=(short)h; lo[3]=(short)s;
  split2(b.x,h,s); hi[4]=(short)h; lo[4]=(short)s;
  split2(b.y,h,s); hi[5]=(short)h; lo[5]=(short)s;
  split2(b.z,h,s); hi[6]=(short)h; lo[6]=(short)s;
  split2(b.w,h,s); hi[7]=(short)h; lo[7]=(short)s;
}

// ---------------------------------------------------------------------------
// Fused 2-layer LSTM on the MFMA pipe with bf16 hi/lo emulated-fp32 (3-pass).
// Block = 512 threads = 8 waves; NN=16 nodes. Wave w owns gate cols
// 32w..32w+31 (2 N-tiles) of both layers; its W^T fragments (hi/lo) live in
// 112 registers. A = [x|h] hi/lo bf16 planes in LDS. Gates land in
// gs[gate][node] via ds_write_b128 (D: col=lane&15, row=4*(lane>>4)+reg).
// Pipeline per iteration t: G = MFMA{L0(t), L1(t-1)} (shared h0(t-1) frags),
// C = combine both layers (4 cells/thread, cell state in registers).
// ---------------------------------------------------------------------------
__global__ __launch_bounds__(512, 2)
void lstm_mfma(const float* __restrict__ x,
    const float* __restrict__ Wih0, const float* __restrict__ Whh0,
    const float* __restrict__ bih0, const float* __restrict__ bhh0,
    const float* __restrict__ Wih1, const float* __restrict__ Whh1,
    const float* __restrict__ bih1, const float* __restrict__ bhh1,
    float* __restrict__ hout, int n)
{
  const int tid = threadIdx.x;
  const int w   = tid >> 6;     // wave 0..7
  const int l   = tid & 63;
  const int lr  = l & 15;       // row (A) / col (B,D) within tile
  const int lg  = l >> 4;       // k-group 0..3
  const int nA  = blockIdx.x * NN;
  int avail = n - nA; if (avail > NN) avail = NN;

  __shared__ short Ax [2][2][16][40];   // [buf][hi/lo][node][f]   (80B rows)
  __shared__ short Ah0[2][16][72];      // [hi/lo][node][m]        (144B rows)
  __shared__ short Ah1[2][16][72];
  __shared__ float gs0[256][20];        // [gate][node+pad]
  __shared__ float gs1[256][20];

  // ---- weights -> split register fragments (28 frags = 112 VGPR) ----
  bf16x8 B0h[2][3], B0l[2][3], B1h[2][4], B1l[2][4];
  float bias0[2], bias1[2];
#pragma unroll
  for (int h = 0; h < 2; ++h){
    const int col = 32*w + 16*h + lr;
    wsplit(Wih0 + col*FF + 8*lg,      B0h[h][0], B0l[h][0]);  // k 0..31  (x)
    wsplit(Whh0 + col*HH + 8*lg,      B0h[h][1], B0l[h][1]);  // k 32..63 (h0 lo)
    wsplit(Whh0 + col*HH + 32 + 8*lg, B0h[h][2], B0l[h][2]);  // k 64..95 (h0 hi)
    wsplit(Wih1 + col*HH + 8*lg,      B1h[h][0], B1l[h][0]);
    wsplit(Wih1 + col*HH + 32 + 8*lg, B1h[h][1], B1l[h][1]);
    wsplit(Whh1 + col*HH + 8*lg,      B1h[h][2], B1l[h][2]);
    wsplit(Whh1 + col*HH + 32 + 8*lg, B1h[h][3], B1l[h][3]);
    bias0[h] = bih0[col] + bhh0[col];
    bias1[h] = bih1[col] + bhh1[col];
  }
#pragma unroll
  for (int h = 0; h < 2; ++h){
#pragma unroll
    for (int k = 0; k < 3; ++k){ PIN(B0h[h][k]); PIN(B0l[h][k]); }
#pragma unroll
    for (int k = 0; k < 4; ++k){ PIN(B1h[h][k]); PIN(B1l[h][k]); }
  }

  // ---- zero h planes; stage x(0) ----
  {
    short* p0 = &Ah0[0][0][0];
    short* p1 = &Ah1[0][0][0];
    for (int i = tid; i < 2*16*72; i += 512){ p0[i] = 0; p1[i] = 0; }
    const int xnd = tid >> 5, xf = tid & 31;
    float v = (xnd < avail) ? x[((size_t)(nA+xnd)*TT + 0)*FF + xf] : 0.0f;
    unsigned short hh, hl; split2(v, hh, hl);
    Ax[0][0][xnd][xf] = (short)hh;
    Ax[0][1][xnd][xf] = (short)hl;
  }
  float c0a = 0.0f, c0b = 0.0f, c1a = 0.0f, c1b = 0.0f;
  const int m0 = tid >> 4;   // 0..31 ; cells (nd,m0) and (nd,m0+32)
  const int nd = tid & 15;
  __syncthreads();

  for (int t = 0; t < TT; ++t){
    // ================= G phase: MFMA L0(t) and L1(t-1) =================
    const int xnd = tid >> 5, xf = tid & 31;
    const int tp = t + 1;
    float xv = 0.0f;
    if (tp < TT && xnd < avail) xv = x[((size_t)(nA+xnd)*TT + tp)*FF + xf];

    bf16x8 axh  = *(const bf16x8*)&Ax[t&1][0][lr][8*lg];
    bf16x8 axl  = *(const bf16x8*)&Ax[t&1][1][lr][8*lg];
    bf16x8 h0ah = *(const bf16x8*)&Ah0[0][lr][8*lg];       // h0(t-1) k 0..31
    bf16x8 h0al = *(const bf16x8*)&Ah0[1][lr][8*lg];
    bf16x8 h0bh = *(const bf16x8*)&Ah0[0][lr][32+8*lg];    // h0(t-1) k 32..63
    bf16x8 h0bl = *(const bf16x8*)&Ah0[1][lr][32+8*lg];

#pragma unroll
    for (int h = 0; h < 2; ++h){
      f32x4 acc = {bias0[h], bias0[h], bias0[h], bias0[h]};
      MFMA(acc, axl,  B0h[h][0]); MFMA(acc, axh,  B0l[h][0]); MFMA(acc, axh,  B0h[h][0]);
      MFMA(acc, h0al, B0h[h][1]); MFMA(acc, h0ah, B0l[h][1]); MFMA(acc, h0ah, B0h[h][1]);
      MFMA(acc, h0bl, B0h[h][2]); MFMA(acc, h0bh, B0l[h][2]); MFMA(acc, h0bh, B0h[h][2]);
      *(f32x4*)&gs0[32*w + 16*h + lr][4*lg] = acc;
    }
    if (t > 0){
      bf16x8 h1ah = *(const bf16x8*)&Ah1[0][lr][8*lg];     // h1(t-2)
      bf16x8 h1al = *(const bf16x8*)&Ah1[1][lr][8*lg];
      bf16x8 h1bh = *(const bf16x8*)&Ah1[0][lr][32+8*lg];
      bf16x8 h1bl = *(const bf16x8*)&Ah1[1][lr][32+8*lg];
#pragma unroll
      for (int h = 0; h < 2; ++h){
        f32x4 acc = {bias1[h], bias1[h], bias1[h], bias1[h]};
        MFMA(acc, h0al, B1h[h][0]); MFMA(acc, h0ah, B1l[h][0]); MFMA(acc, h0ah, B1h[h][0]);
        MFMA(acc, h0bl, B1h[h][1]); MFMA(acc, h0bh, B1l[h][1]); MFMA(acc, h0bh, B1h[h][1]);
        MFMA(acc, h1al, B1h[h][2]); MFMA(acc, h1ah, B1l[h][2]); MFMA(acc, h1ah, B1h[h][2]);
        MFMA(acc, h1bl, B1h[h][3]); MFMA(acc, h1bh, B1l[h][3]); MFMA(acc, h1bh, B1h[h][3]);
        *(f32x4*)&gs1[32*w + 16*h + lr][4*lg] = acc;
      }
    }
    if (tp < TT){  // write x(t+1) split (load latency hidden under MFMA block)
      unsigned short hh, hl; split2(xv, hh, hl);
      Ax[tp&1][0][xnd][xf] = (short)hh;
      Ax[tp&1][1][xnd][xf] = (short)hl;
    }
    __syncthreads();

    // ================= C phase: combine L0(t) and L1(t-1) =================
    {
      float gi = gs0[m0][nd], gf = gs0[m0+64][nd], gg = gs0[m0+128][nd], go = gs0[m0+192][nd];
      c0a = sigm(gf)*c0a + sigm(gi)*ftanh(gg);
      float hv = sigm(go)*ftanh(c0a);
      unsigned short hh, hl; split2(hv, hh, hl);
      Ah0[0][nd][m0] = (short)hh; Ah0[1][nd][m0] = (short)hl;
    }
    {
      const int m1 = m0 + 32;
      float gi = gs0[m1][nd], gf = gs0[m1+64][nd], gg = gs0[m1+128][nd], go = gs0[m1+192][nd];
      c0b = sigm(gf)*c0b + sigm(gi)*ftanh(gg);
      float hv = sigm(go)*ftanh(c0b);
      unsigned short hh, hl; split2(hv, hh, hl);
      Ah0[0][nd][m1] = (short)hh; Ah0[1][nd][m1] = (short)hl;
    }
    if (t > 0){
      {
        float gi = gs1[m0][nd], gf = gs1[m0+64][nd], gg = gs1[m0+128][nd], go = gs1[m0+192][nd];
        c1a = sigm(gf)*c1a + sigm(gi)*ftanh(gg);
        float hv = sigm(go)*ftanh(c1a);
        unsigned short hh, hl; split2(hv, hh, hl);
        Ah1[0][nd][m0] = (short)hh; Ah1[1][nd][m0] = (short)hl;
      }
      {
        const int m1 = m0 + 32;
        float gi = gs1[m1][nd], gf = gs1[m1+64][nd], gg = gs1[m1+128][nd], go = gs1[m1+192][nd];
        c1b = sigm(gf)*c1b + sigm(gi)*ftanh(gg);
        float hv = sigm(go)*ftanh(c1b);
        unsigned short hh, hl; split2(hv, hh, hl);
        Ah1[0][nd][m1] = (short)hh; Ah1[1][nd][m1] = (short)hl;
      }
    }
    __syncthreads();
  }

  // ================= epilogue: L1(TT-1) gates + final combine =================
  {
    bf16x8 h0ah = *(const bf16x8*)&Ah0[0][lr][8*lg];     // h0(TT-1)
    bf16x8 h0al = *(const bf16x8*)&Ah0[1][lr][8*lg];
    bf16x8 h0bh = *(const bf16x8*)&Ah0[0][lr][32+8*lg];
    bf16x8 h0bl = *(const bf16x8*)&Ah0[1][lr][32+8*lg];
    bf16x8 h1ah = *(const bf16x8*)&Ah1[0][lr][8*lg];     // h1(TT-2)
    bf16x8 h1al = *(const bf16x8*)&Ah1[1][lr][8*lg];
    bf16x8 h1bh = *(const bf16x8*)&Ah1[0][lr][32+8*lg];
    bf16x8 h1bl = *(const bf16x8*)&Ah1[1][lr][32+8*lg];
#pragma unroll
    for (int h = 0; h < 2; ++h){
      f32x4 acc = {bias1[h], bias1[h], bias1[h], bias1[h]};
      MFMA(acc, h0al, B1h[h][0]); MFMA(acc, h0ah, B1l[h][0]); MFMA(acc, h0ah, B1h[h][0]);
      MFMA(acc, h0bl, B1h[h][1]); MFMA(acc, h0bh, B1l[h][1]); MFMA(acc, h0bh, B1h[h][1]);
      MFMA(acc, h1al, B1h[h][2]); MFMA(acc, h1ah, B1l[h][2]); MFMA(acc, h1ah, B1h[h][2]);
      MFMA(acc, h1bl, B1h[h][3]); MFMA(acc, h1bh, B1l[h][3]); MFMA(acc, h1bh, B1h[h][3]);
      *(f32x4*)&gs1[32*w + 16*h + lr][4*lg] = acc;
    }
  }
  __syncthreads();
  {
    const int node = nA + nd;
    {
      float gi = gs1[m0][nd], gf = gs1[m0+64][nd], gg = gs1[m0+128][nd], go = gs1[m0+192][nd];
      c1a = sigm(gf)*c1a + sigm(gi)*ftanh(gg);
      float hv = sigm(go)*ftanh(c1a);
      if (node < n) hout[(size_t)node*HH + m0] = hv;
    }
    {
      const int m1 = m0 + 32;
      float gi = gs1[m1][nd], gf = gs1[m1+64][nd], gg = gs1[m1+128][nd], go = gs1[m1+192][nd];
      c1b = sigm(gf)*c1b + sigm(gi)*ftanh(gg);
      float hv = sigm(go)*ftanh(c1b);
      if (node < n) hout[(size_t)node*HH + m1] = hv;
    }
  }
}

// ---------------------------------------------------------------------------
// GCN support kernels (unchanged — not the bottleneck)
// ---------------------------------------------------------------------------
__global__ void k_count(const int* __restrict__ dst, int E, int* __restrict__ cnt)
{
  int e = blockIdx.x * blockDim.x + threadIdx.x;
  if (e < E) atomicAdd(&cnt[dst[e]], 1);
}

__global__ void k_scan_build(const int* __restrict__ cnt, int n,
                             int* __restrict__ offs, int* __restrict__ cursor,
                             float* __restrict__ dinv)
{
  __shared__ int part[1024];
  const int tid = threadIdx.x;
  const int per = (n + 1023) >> 10;
  const int base = tid * per;
  int s = 0;
  for (int i = 0; i < per; ++i) { int idx = base + i; if (idx < n) s += cnt[idx]; }
  part[tid] = s;
  __syncthreads();
  for (int off = 1; off < 1024; off <<= 1) {
    int v = 0;
    if (tid >= off) v = part[tid - off];
    __syncthreads();
    part[tid] += v;
    __syncthreads();
  }
  int run = part[tid] - s;
  for (int i = 0; i < per; ++i) {
    int idx = base + i;
    if (idx < n) {
      offs[idx] = run; cursor[idx] = run;
      int c = cnt[idx];
      dinv[idx] = 1.0f / sqrtf((float)(c + 1));
      run += c;
    }
  }
}

__global__ void k_fill(const int* __restrict__ src, const int* __restrict__ dst,
                       int E, int* __restrict__ cursor, int* __restrict__ csr)
{
  int e = blockIdx.x * blockDim.x + threadIdx.x;
  if (e < E) {
    int d = dst[e];
    int pos = atomicAdd(&cursor[d], 1);
    csr[pos] = src[e];
  }
}

template <int K, int M>
__global__ void k_xw(const float* __restrict__ A, const float* __restrict__ W,
                     float* __restrict__ out, int n)
{
  int idx = blockIdx.x * blockDim.x + threadIdx.x;
  int row = idx / M, col = idx % M;
  if (row >= n) return;
  const float* a = A + (size_t)row * K;
  float acc = 0.0f;
#pragma unroll
  for (int k = 0; k < K; ++k) acc = fmaf(a[k], W[k*M + col], acc);
  out[(size_t)row*M + col] = acc;
}

template <int FD>
__global__ void k_agg(const float* __restrict__ xw, const int* __restrict__ offs,
                      const int* __restrict__ cnt, const int* __restrict__ csr,
                      const float* __restrict__ dinv, const float* __restrict__ b,
                      float* __restrict__ out, int n)
{
  int gidx = blockIdx.x * blockDim.x + threadIdx.x;
  int node = gidx / FD, lane = gidx % FD;
  if (node >= n) return;
  const float di = dinv[node];
  float acc = xw[(size_t)node*FD + lane] * di * di;
  const int s0 = offs[node], e0 = s0 + cnt[node];
  for (int p = s0; p < e0; ++p) {
    int s = csr[p];
    acc = fmaf(xw[(size_t)s*FD + lane], dinv[s] * di, acc);
  }
  out[(size_t)node*FD + lane] = fmaxf(acc + b[lane], 0.0f);
}

__global__ void k_fc(const float* __restrict__ g2, const int* __restrict__ sid,
                     const float* __restrict__ fcW, const float* __restrict__ fcb,
                     float* __restrict__ out, int n)
{
  int i = blockIdx.x * blockDim.x + threadIdx.x;
  if (i >= n) return;
  const float* row = g2 + (size_t)sid[i] * GG2;
  float acc = fcb[0];
#pragma unroll
  for (int f = 0; f < GG2; ++f) acc = fmaf(row[f], fcW[f], acc);
  out[i] = acc;
}

// ---------------------------------------------------------------------------
extern "C" void kernel_launch(void* const* d_in, const int* in_sizes, int n_in,
                              void* d_out, int out_size, void* d_ws, size_t ws_size,
                              hipStream_t stream)
{
  const float* x    = (const float*)d_in[0];
  const int*   sid  = (const int*)  d_in[1];
  const int*   eidx = (const int*)  d_in[2];
  const float* Wih0 = (const float*)d_in[3];
  const float* Whh0 = (const float*)d_in[4];
  const float* bih0 = (const float*)d_in[5];
  const float* bhh0 = (const float*)d_in[6];
  const float* Wih1 = (const float*)d_in[7];
  const float* Whh1 = (const float*)d_in[8];
  const float* bih1 = (const float*)d_in[9];
  const float* bhh1 = (const float*)d_in[10];
  const float* g1W  = (const float*)d_in[11];
  const float* g1b  = (const float*)d_in[12];
  const float* g2W  = (const float*)d_in[13];
  const float* g2b  = (const float*)d_in[14];
  const float* fcW  = (const float*)d_in[15];
  const float* fcb  = (const float*)d_in[16];

  const int n = in_sizes[1];
  const int E = in_sizes[2] / 2;
  float* out = (float*)d_out;

  char* w = (char*)d_ws;
  auto carve = [&](size_t bytes) -> void* {
    void* p = (void*)w; w += (bytes + 255) & ~(size_t)255; return p;
  };
  float* hfin   = (float*)carve((size_t)n * HH * 4);
  int*   cnt    = (int*)  carve((size_t)n * 4);
  int*   offs   = (int*)  carve((size_t)n * 4);
  int*   cursor = (int*)  carve((size_t)n * 4);
  float* dinv   = (float*)carve((size_t)n * 4);
  int*   csr    = (int*)  carve((size_t)E * 4);
  float* xw1    = (float*)carve((size_t)n * GG1 * 4);
  float* g1     = (float*)carve((size_t)n * GG1 * 4);
  float* xw2    = (float*)carve((size_t)n * GG2 * 4);
  float* g2     = (float*)carve((size_t)n * GG2 * 4);

  const int* src = eidx;
  const int* dst = eidx + E;

  lstm_mfma<<<(n + NN - 1) / NN, 512, 0, stream>>>(x, Wih0, Whh0, bih0, bhh0,
                                                   Wih1, Whh1, bih1, bhh1, hfin, n);

  hipMemsetAsync(cnt, 0, (size_t)n * 4, stream);
  k_count<<<(E + 255) / 256, 256, 0, stream>>>(dst, E, cnt);
  k_scan_build<<<1, 1024, 0, stream>>>(cnt, n, offs, cursor, dinv);
  k_fill<<<(E + 255) / 256, 256, 0, stream>>>(src, dst, E, cursor, csr);

  k_xw<HH, GG1><<<((size_t)n * GG1 + 255) / 256, 256, 0, stream>>>(hfin, g1W, xw1, n);
  k_agg<GG1><<<((size_t)n * GG1 + 255) / 256, 256, 0, stream>>>(xw1, offs, cnt, csr, dinv, g1b, g1, n);

  k_xw<GG1, GG2><<<((size_t)n * GG2 + 255) / 256, 256, 0, stream>>>(g1, g2W, xw2, n);
  k_agg<GG2><<<((size_t)n * GG2 + 255) / 256, 256, 0, stream>>>(xw2, offs, cnt, csr, dinv, g2b, g2, n);

  k_fc<<<(n + 255) / 256, 256, 0, stream>>>(g2, sid, fcW, fcb, out, n);
}

// Round 8
// 692.888 us; speedup vs baseline: 4.5484x; 1.2097x over previous
//
#include <hip/hip_runtime.h>
#include <math.h>

#define TT 64
#define FF 32
#define HH 64
#define NN 16     // nodes per block
#define GG1 64
#define GG2 32

typedef float f32x4 __attribute__((ext_vector_type(4)));
typedef short bf16x8 __attribute__((ext_vector_type(8)));

__device__ __forceinline__ float fexp2(float x){ return __builtin_amdgcn_exp2f(x); }
__device__ __forceinline__ float frcp (float x){ return __builtin_amdgcn_rcpf(x); }
__device__ __forceinline__ float sigm (float v){ return frcp(1.0f + fexp2(-1.442695041f*v)); }
__device__ __forceinline__ float ftanh(float v){ return fmaf(-2.0f, frcp(1.0f + fexp2(2.885390082f*v)), 1.0f); }

// lane <-> lane^8 exchange within rows of 16, on the VALU (DPP row_ror:8)
__device__ __forceinline__ float xor8(float v){
  int a = __builtin_bit_cast(int, v);
  int b = __builtin_amdgcn_update_dpp(0, a, 0x128, 0xF, 0xF, true);
  return __builtin_bit_cast(float, b);
}

// round-to-nearest-even fp32 -> bf16 bits
__device__ __forceinline__ unsigned short bf16rn(float x){
  unsigned u = __builtin_bit_cast(unsigned, x);
  return (unsigned short)((u + 0x7FFFu + ((u >> 16) & 1u)) >> 16);
}
// split x = hi + lo (both bf16-representable); hi = RN(x)
__device__ __forceinline__ void split2(float x, unsigned short& h, unsigned short& l){
  unsigned u = __builtin_bit_cast(unsigned, x);
  unsigned hr = (u + 0x7FFFu + ((u >> 16) & 1u)) & 0xFFFF0000u;
  h = (unsigned short)(hr >> 16);
  l = bf16rn(x - __builtin_bit_cast(float, hr));
}

#define PIN(v) asm volatile("" : "+v"(v))
#define MFMA(acc, a, b) (acc) = __builtin_amdgcn_mfma_f32_16x16x32_bf16((a), (b), (acc), 0, 0, 0)

// load 8 consecutive fp32 and split into hi/lo bf16 fragments
__device__ __forceinline__ void wsplit(const float* p, bf16x8& hi, bf16x8& lo){
  float4 a = *(const float4*)p;
  float4 b = *(const float4*)(p + 4);
  unsigned short h, s;
  split2(a.x,h,s); hi[0]=(short)h; lo[0]=(short)s;
  split2(a.y,h,s); hi[1]=(short)h; lo[1]=(short)s;
  split2(a.z,h,s); hi[2]=(short)h; lo[2]=(short)s;
  split2(a.w,h,s); hi[3]=(short)h; lo[3]=(short)s;
  split2(b.x,h,s); hi[4]=(short)h; lo[4]=(short)s;
  split2(b.y,h,s); hi[5]=(short)h; lo[5]=(short)s;
  split2(b.z,h,s); hi[6]=(short)h; lo[6]=(short)s;
  split2(b.w,h,s); hi[7]=(short)h; lo[7]=(short)s;
}

// ---------------------------------------------------------------------------
// Fused 2-layer LSTM on MFMA with bf16 hi/lo emulated-fp32 (3-pass), and
// IN-REGISTER gate combine: wave w's two B-tiles carry cols {i:8w+j, f:64+8w+j}
// and {g:128+8w+j, o:192+8w+j}, so after MFMA a single DPP row_ror:8 exchange
// gives each lane (i,f,g,o) for 2 nodes of gate index m=8w+(lane&7). No gs
// LDS round-trip, ONE barrier per timestep (h planes double-buffered).
// ---------------------------------------------------------------------------
__global__ __launch_bounds__(512, 2)
void lstm_mfma(const float* __restrict__ x,
    const float* __restrict__ Wih0, const float* __restrict__ Whh0,
    const float* __restrict__ bih0, const float* __restrict__ bhh0,
    const float* __restrict__ Wih1, const float* __restrict__ Whh1,
    const float* __restrict__ bih1, const float* __restrict__ bhh1,
    float* __restrict__ hout, int n)
{
  const int tid = threadIdx.x;
  const int w   = tid >> 6;     // wave 0..7
  const int l   = tid & 63;
  const int lr  = l & 15;       // A row (node) / B,D col-slot
  const int lg  = l >> 4;       // k-group 0..3
  const int nA  = blockIdx.x * NN;
  int avail = n - nA; if (avail > NN) avail = NN;

  __shared__ short Ax[2][2][16][40];   // [buf][hi/lo][node][f]   80B rows
  __shared__ short H0[2][2][16][88];   // [buf][hi/lo][node][m]  176B rows
  __shared__ short H1[2][2][16][88];

  // ---- gate-col mapping: tile0 = (i|f), tile1 = (g|o) for m = 8w+(lr&7) ----
  const int jm   = lr & 7;
  const int col0 = (lr < 8) ? (8*w + jm) : (64  + 8*w + jm);   // i | f
  const int col1 = (lr < 8) ? (128 + 8*w + jm) : (192 + 8*w + jm); // g | o

  // ---- weights -> split register fragments (28 frags = 112 VGPR) ----
  bf16x8 W0h[2][3], W0l[2][3], W1h[2][4], W1l[2][4];
  float bias0[2], bias1[2];
#pragma unroll
  for (int h = 0; h < 2; ++h){
    const int col = h ? col1 : col0;
    wsplit(Wih0 + col*FF + 8*lg,      W0h[h][0], W0l[h][0]);  // x   k 0..31
    wsplit(Whh0 + col*HH + 8*lg,      W0h[h][1], W0l[h][1]);  // h0  k 0..31
    wsplit(Whh0 + col*HH + 32 + 8*lg, W0h[h][2], W0l[h][2]);  // h0  k 32..63
    wsplit(Wih1 + col*HH + 8*lg,      W1h[h][0], W1l[h][0]);
    wsplit(Wih1 + col*HH + 32 + 8*lg, W1h[h][1], W1l[h][1]);
    wsplit(Whh1 + col*HH + 8*lg,      W1h[h][2], W1l[h][2]);
    wsplit(Whh1 + col*HH + 32 + 8*lg, W1h[h][3], W1l[h][3]);
    bias0[h] = bih0[col] + bhh0[col];
    bias1[h] = bih1[col] + bhh1[col];
  }
#pragma unroll
  for (int h = 0; h < 2; ++h){
#pragma unroll
    for (int k = 0; k < 3; ++k){ PIN(W0h[h][k]); PIN(W0l[h][k]); }
#pragma unroll
    for (int k = 0; k < 4; ++k){ PIN(W1h[h][k]); PIN(W1l[h][k]); }
  }

  // ---- zero h planes; stage x(0) ----
  {
    short* p0 = &H0[0][0][0][0];
    short* p1 = &H1[0][0][0][0];
    for (int i = tid; i < 2*2*16*88; i += 512){ p0[i] = 0; p1[i] = 0; }
    const int xnd = tid >> 5, xf = tid & 31;
    float v = (xnd < avail) ? x[((size_t)(nA+xnd)*TT + 0)*FF + xf] : 0.0f;
    unsigned short hh, hl; split2(v, hh, hl);
    Ax[0][0][xnd][xf] = (short)hh;
    Ax[0][1][xnd][xf] = (short)hl;
  }
  // cell state: 2 cells per layer per thread at (node, m):
  //   nodes na=4*lg+(lr<8?0:2), nb=na+1 ; m = 8w+jm
  const int na = 4*lg + ((lr < 8) ? 0 : 2);
  const int nb = na + 1;
  const int m  = 8*w + jm;
  const bool lo8 = (lr < 8);
  float c0a = 0.0f, c0b = 0.0f, c1a = 0.0f, c1b = 0.0f;
  __syncthreads();

  for (int t = 0; t < TT; ++t){
    const int rd0 = (t & 1) ^ 1;   // h0(t-1)
    const int wr0 =  t & 1;        // h0(t)
    const int rd1 =  t & 1;        // h1(t-2)
    const int wr1 = (t & 1) ^ 1;   // h1(t-1)

    // issue x(t+1) load early (consumed after MFMAs)
    const int xnd = tid >> 5, xf = tid & 31;
    const int tp = t + 1;
    float xv = 0.0f;
    if (tp < TT && xnd < avail) xv = x[((size_t)(nA+xnd)*TT + tp)*FF + xf];

    // ---- A fragments ----
    bf16x8 axh  = *(const bf16x8*)&Ax[t&1][0][lr][8*lg];
    bf16x8 axl  = *(const bf16x8*)&Ax[t&1][1][lr][8*lg];
    bf16x8 h0ah = *(const bf16x8*)&H0[rd0][0][lr][8*lg];
    bf16x8 h0al = *(const bf16x8*)&H0[rd0][1][lr][8*lg];
    bf16x8 h0bh = *(const bf16x8*)&H0[rd0][0][lr][32+8*lg];
    bf16x8 h0bl = *(const bf16x8*)&H0[rd0][1][lr][32+8*lg];

    // ---- L0 gates(t): two tiles (i|f) and (g|o) ----
    f32x4 acc0 = {bias0[0], bias0[0], bias0[0], bias0[0]};
    f32x4 acc1 = {bias0[1], bias0[1], bias0[1], bias0[1]};
    MFMA(acc0, axl,  W0h[0][0]); MFMA(acc0, axh,  W0l[0][0]); MFMA(acc0, axh,  W0h[0][0]);
    MFMA(acc1, axl,  W0h[1][0]); MFMA(acc1, axh,  W0l[1][0]); MFMA(acc1, axh,  W0h[1][0]);
    MFMA(acc0, h0al, W0h[0][1]); MFMA(acc0, h0ah, W0l[0][1]); MFMA(acc0, h0ah, W0h[0][1]);
    MFMA(acc1, h0al, W0h[1][1]); MFMA(acc1, h0ah, W0l[1][1]); MFMA(acc1, h0ah, W0h[1][1]);
    MFMA(acc0, h0bl, W0h[0][2]); MFMA(acc0, h0bh, W0l[0][2]); MFMA(acc0, h0bh, W0h[0][2]);
    MFMA(acc1, h0bl, W0h[1][2]); MFMA(acc1, h0bh, W0l[1][2]); MFMA(acc1, h0bh, W0h[1][2]);

    // ---- L1 gates(t-1) ----
    f32x4 acd0, acd1;
    if (t > 0){
      bf16x8 h1ah = *(const bf16x8*)&H1[rd1][0][lr][8*lg];
      bf16x8 h1al = *(const bf16x8*)&H1[rd1][1][lr][8*lg];
      bf16x8 h1bh = *(const bf16x8*)&H1[rd1][0][lr][32+8*lg];
      bf16x8 h1bl = *(const bf16x8*)&H1[rd1][1][lr][32+8*lg];
      acd0 = (f32x4){bias1[0], bias1[0], bias1[0], bias1[0]};
      acd1 = (f32x4){bias1[1], bias1[1], bias1[1], bias1[1]};
      MFMA(acd0, h0al, W1h[0][0]); MFMA(acd0, h0ah, W1l[0][0]); MFMA(acd0, h0ah, W1h[0][0]);
      MFMA(acd1, h0al, W1h[1][0]); MFMA(acd1, h0ah, W1l[1][0]); MFMA(acd1, h0ah, W1h[1][0]);
      MFMA(acd0, h0bl, W1h[0][1]); MFMA(acd0, h0bh, W1l[0][1]); MFMA(acd0, h0bh, W1h[0][1]);
      MFMA(acd1, h0bl, W1h[1][1]); MFMA(acd1, h0bh, W1l[1][1]); MFMA(acd1, h0bh, W1h[1][1]);
      MFMA(acd0, h1al, W1h[0][2]); MFMA(acd0, h1ah, W1l[0][2]); MFMA(acd0, h1ah, W1h[0][2]);
      MFMA(acd1, h1al, W1h[1][2]); MFMA(acd1, h1ah, W1l[1][2]); MFMA(acd1, h1ah, W1h[1][2]);
      MFMA(acd0, h1bl, W1h[0][3]); MFMA(acd0, h1bh, W1l[0][3]); MFMA(acd0, h1bh, W1h[0][3]);
      MFMA(acd1, h1bl, W1h[1][3]); MFMA(acd1, h1bh, W1l[1][3]); MFMA(acd1, h1bh, W1h[1][3]);
    }

    // stage x(t+1) split (hidden under MFMA latency)
    if (tp < TT){
      unsigned short hh, hl; split2(xv, hh, hl);
      Ax[tp&1][0][xnd][xf] = (short)hh;
      Ax[tp&1][1][xnd][xf] = (short)hl;
    }

    // ---- in-register combine L0(t): exchange halves via DPP ----
    {
      f32x4 s0, s1;
      s0[0]=xor8(acc0[0]); s0[1]=xor8(acc0[1]); s0[2]=xor8(acc0[2]); s0[3]=xor8(acc0[3]);
      s1[0]=xor8(acc1[0]); s1[1]=xor8(acc1[1]); s1[2]=xor8(acc1[2]); s1[3]=xor8(acc1[3]);
      float gi_a = lo8 ? acc0[0] : s0[2],  gi_b = lo8 ? acc0[1] : s0[3];
      float gf_a = lo8 ? s0[0] : acc0[2],  gf_b = lo8 ? s0[1] : acc0[3];
      float gg_a = lo8 ? acc1[0] : s1[2],  gg_b = lo8 ? acc1[1] : s1[3];
      float go_a = lo8 ? s1[0] : acc1[2],  go_b = lo8 ? s1[1] : acc1[3];
      c0a = sigm(gf_a)*c0a + sigm(gi_a)*ftanh(gg_a);
      float ha = sigm(go_a)*ftanh(c0a);
      c0b = sigm(gf_b)*c0b + sigm(gi_b)*ftanh(gg_b);
      float hb = sigm(go_b)*ftanh(c0b);
      unsigned short hh, hl;
      split2(ha, hh, hl); H0[wr0][0][na][m] = (short)hh; H0[wr0][1][na][m] = (short)hl;
      split2(hb, hh, hl); H0[wr0][0][nb][m] = (short)hh; H0[wr0][1][nb][m] = (short)hl;
    }
    // ---- in-register combine L1(t-1) ----
    if (t > 0){
      f32x4 s0, s1;
      s0[0]=xor8(acd0[0]); s0[1]=xor8(acd0[1]); s0[2]=xor8(acd0[2]); s0[3]=xor8(acd0[3]);
      s1[0]=xor8(acd1[0]); s1[1]=xor8(acd1[1]); s1[2]=xor8(acd1[2]); s1[3]=xor8(acd1[3]);
      float gi_a = lo8 ? acd0[0] : s0[2],  gi_b = lo8 ? acd0[1] : s0[3];
      float gf_a = lo8 ? s0[0] : acd0[2],  gf_b = lo8 ? s0[1] : acd0[3];
      float gg_a = lo8 ? acd1[0] : s1[2],  gg_b = lo8 ? acd1[1] : s1[3];
      float go_a = lo8 ? s1[0] : acd1[2],  go_b = lo8 ? s1[1] : acd1[3];
      c1a = sigm(gf_a)*c1a + sigm(gi_a)*ftanh(gg_a);
      float ha = sigm(go_a)*ftanh(c1a);
      c1b = sigm(gf_b)*c1b + sigm(gi_b)*ftanh(gg_b);
      float hb = sigm(go_b)*ftanh(c1b);
      unsigned short hh, hl;
      split2(ha, hh, hl); H1[wr1][0][na][m] = (short)hh; H1[wr1][1][na][m] = (short)hl;
      split2(hb, hh, hl); H1[wr1][0][nb][m] = (short)hh; H1[wr1][1][nb][m] = (short)hl;
    }
    __syncthreads();   // single barrier per timestep
  }

  // ---- epilogue: L1 gates(TT-1) + combine -> hout ----
  {
    const int rd0 = (TT-1) & 1;      // h0(TT-1)
    const int rd1 =  TT & 1;         // h1(TT-2)
    bf16x8 h0ah = *(const bf16x8*)&H0[rd0][0][lr][8*lg];
    bf16x8 h0al = *(const bf16x8*)&H0[rd0][1][lr][8*lg];
    bf16x8 h0bh = *(const bf16x8*)&H0[rd0][0][lr][32+8*lg];
    bf16x8 h0bl = *(const bf16x8*)&H0[rd0][1][lr][32+8*lg];
    bf16x8 h1ah = *(const bf16x8*)&H1[rd1][0][lr][8*lg];
    bf16x8 h1al = *(const bf16x8*)&H1[rd1][1][lr][8*lg];
    bf16x8 h1bh = *(const bf16x8*)&H1[rd1][0][lr][32+8*lg];
    bf16x8 h1bl = *(const bf16x8*)&H1[rd1][1][lr][32+8*lg];
    f32x4 acd0 = {bias1[0], bias1[0], bias1[0], bias1[0]};
    f32x4 acd1 = {bias1[1], bias1[1], bias1[1], bias1[1]};
    MFMA(acd0, h0al, W1h[0][0]); MFMA(acd0, h0ah, W1l[0][0]); MFMA(acd0, h0ah, W1h[0][0]);
    MFMA(acd1, h0al, W1h[1][0]); MFMA(acd1, h0ah, W1l[1][0]); MFMA(acd1, h0ah, W1h[1][0]);
    MFMA(acd0, h0bl, W1h[0][1]); MFMA(acd0, h0bh, W1l[0][1]); MFMA(acd0, h0bh, W1h[0][1]);
    MFMA(acd1, h0bl, W1h[1][1]); MFMA(acd1, h0bh, W1l[1][1]); MFMA(acd1, h0bh, W1h[1][1]);
    MFMA(acd0, h1al, W1h[0][2]); MFMA(acd0, h1ah, W1l[0][2]); MFMA(acd0, h1ah, W1h[0][2]);
    MFMA(acd1, h1al, W1h[1][2]); MFMA(acd1, h1ah, W1l[1][2]); MFMA(acd1, h1ah, W1h[1][2]);
    MFMA(acd0, h1bl, W1h[0][3]); MFMA(acd0, h1bh, W1l[0][3]); MFMA(acd0, h1bh, W1h[0][3]);
    MFMA(acd1, h1bl, W1h[1][3]); MFMA(acd1, h1bh, W1l[1][3]); MFMA(acd1, h1bh, W1h[1][3]);

    f32x4 s0, s1;
    s0[0]=xor8(acd0[0]); s0[1]=xor8(acd0[1]); s0[2]=xor8(acd0[2]); s0[3]=xor8(acd0[3]);
    s1[0]=xor8(acd1[0]); s1[1]=xor8(acd1[1]); s1[2]=xor8(acd1[2]); s1[3]=xor8(acd1[3]);
    float gi_a = lo8 ? acd0[0] : s0[2],  gi_b = lo8 ? acd0[1] : s0[3];
    float gf_a = lo8 ? s0[0] : acd0[2],  gf_b = lo8 ? s0[1] : acd0[3];
    float gg_a = lo8 ? acd1[0] : s1[2],  gg_b = lo8 ? acd1[1] : s1[3];
    float go_a = lo8 ? s1[0] : acd1[2],  go_b = lo8 ? s1[1] : acd1[3];
    c1a = sigm(gf_a)*c1a + sigm(gi_a)*ftanh(gg_a);
    float ha = sigm(go_a)*ftanh(c1a);
    c1b = sigm(gf_b)*c1b + sigm(gi_b)*ftanh(gg_b);
    float hb = sigm(go_b)*ftanh(c1b);
    if (nA + na < n) hout[(size_t)(nA+na)*HH + m] = ha;
    if (nA + nb < n) hout[(size_t)(nA+nb)*HH + m] = hb;
  }
}

// ---------------------------------------------------------------------------
// GCN support kernels (unchanged — not the bottleneck)
// ---------------------------------------------------------------------------
__global__ void k_count(const int* __restrict__ dst, int E, int* __restrict__ cnt)
{
  int e = blockIdx.x * blockDim.x + threadIdx.x;
  if (e < E) atomicAdd(&cnt[dst[e]], 1);
}

__global__ void k_scan_build(const int* __restrict__ cnt, int n,
                             int* __restrict__ offs, int* __restrict__ cursor,
                             float* __restrict__ dinv)
{
  __shared__ int part[1024];
  const int tid = threadIdx.x;
  const int per = (n + 1023) >> 10;
  const int base = tid * per;
  int s = 0;
  for (int i = 0; i < per; ++i) { int idx = base + i; if (idx < n) s += cnt[idx]; }
  part[tid] = s;
  __syncthreads();
  for (int off = 1; off < 1024; off <<= 1) {
    int v = 0;
    if (tid >= off) v = part[tid - off];
    __syncthreads();
    part[tid] += v;
    __syncthreads();
  }
  int run = part[tid] - s;
  for (int i = 0; i < per; ++i) {
    int idx = base + i;
    if (idx < n) {
      offs[idx] = run; cursor[idx] = run;
      int c = cnt[idx];
      dinv[idx] = 1.0f / sqrtf((float)(c + 1));
      run += c;
    }
  }
}

__global__ void k_fill(const int* __restrict__ src, const int* __restrict__ dst,
                       int E, int* __restrict__ cursor, int* __restrict__ csr)
{
  int e = blockIdx.x * blockDim.x + threadIdx.x;
  if (e < E) {
    int d = dst[e];
    int pos = atomicAdd(&cursor[d], 1);
    csr[pos] = src[e];
  }
}

template <int K, int M>
__global__ void k_xw(const float* __restrict__ A, const float* __restrict__ W,
                     float* __restrict__ out, int n)
{
  int idx = blockIdx.x * blockDim.x + threadIdx.x;
  int row = idx / M, col = idx % M;
  if (row >= n) return;
  const float* a = A + (size_t)row * K;
  float acc = 0.0f;
#pragma unroll
  for (int k = 0; k < K; ++k) acc = fmaf(a[k], W[k*M + col], acc);
  out[(size_t)row*M + col] = acc;
}

template <int FD>
__global__ void k_agg(const float* __restrict__ xw, const int* __restrict__ offs,
                      const int* __restrict__ cnt, const int* __restrict__ csr,
                      const float* __restrict__ dinv, const float* __restrict__ b,
                      float* __restrict__ out, int n)
{
  int gidx = blockIdx.x * blockDim.x + threadIdx.x;
  int node = gidx / FD, lane = gidx % FD;
  if (node >= n) return;
  const float di = dinv[node];
  float acc = xw[(size_t)node*FD + lane] * di * di;
  const int s0 = offs[node], e0 = s0 + cnt[node];
  for (int p = s0; p < e0; ++p) {
    int s = csr[p];
    acc = fmaf(xw[(size_t)s*FD + lane], dinv[s] * di, acc);
  }
  out[(size_t)node*FD + lane] = fmaxf(acc + b[lane], 0.0f);
}

__global__ void k_fc(const float* __restrict__ g2, const int* __restrict__ sid,
                     const float* __restrict__ fcW, const float* __restrict__ fcb,
                     float* __restrict__ out, int n)
{
  int i = blockIdx.x * blockDim.x + threadIdx.x;
  if (i >= n) return;
  const float* row = g2 + (size_t)sid[i] * GG2;
  float acc = fcb[0];
#pragma unroll
  for (int f = 0; f < GG2; ++f) acc = fmaf(row[f], fcW[f], acc);
  out[i] = acc;
}

// ---------------------------------------------------------------------------
extern "C" void kernel_launch(void* const* d_in, const int* in_sizes, int n_in,
                              void* d_out, int out_size, void* d_ws, size_t ws_size,
                              hipStream_t stream)
{
  const float* x    = (const float*)d_in[0];
  const int*   sid  = (const int*)  d_in[1];
  const int*   eidx = (const int*)  d_in[2];
  const float* Wih0 = (const float*)d_in[3];
  const float* Whh0 = (const float*)d_in[4];
  const float* bih0 = (const float*)d_in[5];
  const float* bhh0 = (const float*)d_in[6];
  const float* Wih1 = (const float*)d_in[7];
  const float* Whh1 = (const float*)d_in[8];
  const float* bih1 = (const float*)d_in[9];
  const float* bhh1 = (const float*)d_in[10];
  const float* g1W  = (const float*)d_in[11];
  const float* g1b  = (const float*)d_in[12];
  const float* g2W  = (const float*)d_in[13];
  const float* g2b  = (const float*)d_in[14];
  const float* fcW  = (const float*)d_in[15];
  const float* fcb  = (const float*)d_in[16];

  const int n = in_sizes[1];
  const int E = in_sizes[2] / 2;
  float* out = (float*)d_out;

  char* w = (char*)d_ws;
  auto carve = [&](size_t bytes) -> void* {
    void* p = (void*)w; w += (bytes + 255) & ~(size_t)255; return p;
  };
  float* hfin   = (float*)carve((size_t)n * HH * 4);
  int*   cnt    = (int*)  carve((size_t)n * 4);
  int*   offs   = (int*)  carve((size_t)n * 4);
  int*   cursor = (int*)  carve((size_t)n * 4);
  float* dinv   = (float*)carve((size_t)n * 4);
  int*   csr    = (int*)  carve((size_t)E * 4);
  float* xw1    = (float*)carve((size_t)n * GG1 * 4);
  float* g1     = (float*)carve((size_t)n * GG1 * 4);
  float* xw2    = (float*)carve((size_t)n * GG2 * 4);
  float* g2     = (float*)carve((size_t)n * GG2 * 4);

  const int* src = eidx;
  const int* dst = eidx + E;

  lstm_mfma<<<(n + NN - 1) / NN, 512, 0, stream>>>(x, Wih0, Whh0, bih0, bhh0,
                                                   Wih1, Whh1, bih1, bhh1, hfin, n);

  hipMemsetAsync(cnt, 0, (size_t)n * 4, stream);
  k_count<<<(E + 255) / 256, 256, 0, stream>>>(dst, E, cnt);
  k_scan_build<<<1, 1024, 0, stream>>>(cnt, n, offs, cursor, dinv);
  k_fill<<<(E + 255) / 256, 256, 0, stream>>>(src, dst, E, cursor, csr);

  k_xw<HH, GG1><<<((size_t)n * GG1 + 255) / 256, 256, 0, stream>>>(hfin, g1W, xw1, n);
  k_agg<GG1><<<((size_t)n * GG1 + 255) / 256, 256, 0, stream>>>(xw1, offs, cnt, csr, dinv, g1b, g1, n);

  k_xw<GG1, GG2><<<((size_t)n * GG2 + 255) / 256, 256, 0, stream>>>(g1, g2W, xw2, n);
  k_agg<GG2><<<((size_t)n * GG2 + 255) / 256, 256, 0, stream>>>(xw2, offs, cnt, csr, dinv, g2b, g2, n);

  k_fc<<<(n + 255) / 256, 256, 0, stream>>>(g2, sid, fcW, fcb, out, n);
}